// Round 4
// baseline (667.432 us; speedup 1.0000x reference)
//
#include <hip/hip_runtime.h>
#include <cmath>

#define N_MET   100000
#define N_RXN   200000
#define E_SUB   400000
#define E_PROD  400000
#define HIDDEN  128
#define MSG_DIM 64
#define DT      0.01f
#define TGRID   32
#define TGP     33
#define NPTS    (TGP * TGP)
#define BPTS    16
#define NB1     ((N_RXN + 255) / 256)          // 782
#define CHUNK   8
#define NCHUNK  ((N_RXN + CHUNK - 1) / CHUNK)  // 25000

__device__ __forceinline__ float fast_tanh(float x) {
    float t = __expf(2.0f * x);
    return 1.0f - 2.0f * __builtin_amdgcn_rcpf(t + 1.0f);
}

__device__ __forceinline__ float softplus_f(float x) {
    return (x > 20.0f) ? x : log1pf(__expf(x));
}

__device__ __forceinline__ float bcastf(float v, int l) {
    return __int_as_float(__builtin_amdgcn_readlane(__float_as_int(v), l));
}

// M[j][d] = sum_m W2[j][m] * V1[m][d]  (128x128), row 128 = b2 @ V1 bias
__global__ void mm_kernel(const float* __restrict__ W2, const float* __restrict__ V1,
                          const float* __restrict__ b2, float* __restrict__ M) {
    int j = blockIdx.x;      // 0..128
    int d = threadIdx.x;     // 0..127
    float acc = 0.0f;
    if (j < HIDDEN) {
        for (int m = 0; m < MSG_DIM; ++m)
            acc = fmaf(W2[j * MSG_DIM + m], V1[m * HIDDEN + d], acc);
        M[j * HIDDEN + d] = acc;
    } else {
        for (int m = 0; m < MSG_DIM; ++m)
            acc = fmaf(b2[m], V1[m * HIDDEN + d], acc);
        M[HIDDEN * HIDDEN + d] = acc;
    }
}

// g-table: t2[(ia*TGP+ib)*64 + l] = { g[l], g[l+64] },
// g(a,b) = tanh(a*W1[0]+b*W1[1]+b1) @ M + bg
__global__ void __launch_bounds__(128)
gtable_kernel(const float* __restrict__ W1, const float* __restrict__ b1,
              const float* __restrict__ M, float* __restrict__ t2f) {
    __shared__ float h_s[HIDDEN];
    int d = threadIdx.x;
    float Mreg[HIDDEN];
    #pragma unroll 8
    for (int j = 0; j < HIDDEN; ++j) Mreg[j] = M[j * HIDDEN + d];
    float bgd = M[HIDDEN * HIDDEN + d];
    float w1a = W1[d], w1b = W1[HIDDEN + d], b1d = b1[d];
    int pend = blockIdx.x * BPTS + BPTS; if (pend > NPTS) pend = NPTS;
    for (int p = blockIdx.x * BPTS; p < pend; ++p) {
        int ia = p / TGP, ib = p % TGP;
        float a = (float)ia * (1.0f / TGRID);
        float b = 0.5f + (float)ib * (1.0f / TGRID);
        h_s[d] = tanhf(fmaf(a, w1a, fmaf(b, w1b, b1d)));
        __syncthreads();
        float acc = bgd;
        #pragma unroll
        for (int j4 = 0; j4 < HIDDEN; j4 += 4) {
            float4 hv = *(const float4*)&h_s[j4];
            acc = fmaf(hv.x, Mreg[j4 + 0], acc);
            acc = fmaf(hv.y, Mreg[j4 + 1], acc);
            acc = fmaf(hv.z, Mreg[j4 + 2], acc);
            acc = fmaf(hv.w, Mreg[j4 + 3], acc);
        }
        if (d < 64) t2f[(p * 64 + d) * 2]            = acc;
        else        t2f[(p * 64 + (d - 64)) * 2 + 1] = acc;
        __syncthreads();
    }
}

__global__ void hist_kernel(const int* __restrict__ rxn_sub, const int* __restrict__ met_sub,
                            const float* __restrict__ x,
                            int* __restrict__ cnt, float* __restrict__ ext_sum) {
    int t = blockIdx.x * blockDim.x + threadIdx.x;
    if (t < E_SUB) {
        int r = rxn_sub[t];
        atomicAdd(&cnt[r], 1);
        atomicAdd(&ext_sum[r], x[met_sub[t] * 8 + 4]);
    }
}

// shfl-based block scan: 1 barrier
__global__ void scan_l1(const int* __restrict__ cnt, int* __restrict__ off,
                        int* __restrict__ bsum) {
    __shared__ int wsum[4];
    int t = threadIdx.x, lane = t & 63, w = t >> 6;
    int i = blockIdx.x * 256 + t;
    int v = (i < N_RXN) ? cnt[i] : 0;
    int s = v;
    #pragma unroll
    for (int d = 1; d < 64; d <<= 1) {
        int u = __shfl_up(s, d);
        if (lane >= d) s += u;
    }
    if (lane == 63) wsum[w] = s;
    __syncthreads();
    int pre = 0;
    #pragma unroll
    for (int q = 0; q < 4; ++q) if (q < w) pre += wsum[q];
    if (i < N_RXN) off[i] = pre + s - v;
    if (t == 255) bsum[blockIdx.x] = pre + s;
}

// single block, 1024 threads, NB1=782 fits in one pass
__global__ void scan_l2(int* __restrict__ bsum) {
    __shared__ int wsum[16];
    int t = threadIdx.x, lane = t & 63, w = t >> 6;
    int v = (t < NB1) ? bsum[t] : 0;
    int s = v;
    #pragma unroll
    for (int d = 1; d < 64; d <<= 1) {
        int u = __shfl_up(s, d);
        if (lane >= d) s += u;
    }
    if (lane == 63) wsum[w] = s;
    __syncthreads();
    int pre = 0;
    #pragma unroll
    for (int q = 0; q < 16; ++q) if (q < w) pre += wsum[q];
    if (t < NB1) bsum[t] = pre + s - v;    // exclusive
}

// finalize scan; zero tot and d_out here (saves a memset + init kernel)
__global__ void scan_l3(int* __restrict__ off, const int* __restrict__ bsum,
                        int* __restrict__ woff, float* __restrict__ tot,
                        float* __restrict__ out) {
    int i = blockIdx.x * blockDim.x + threadIdx.x;
    if (i < N_RXN) {
        int wv = off[i] + bsum[i >> 8];
        off[i] = wv;
        woff[i] = wv;
    }
    if (i < N_MET) { tot[i] = 0.0f; out[i] = 0.0f; }
    if (i == 0) off[N_RXN] = E_SUB;
}

__global__ void scatter_kernel(const int* __restrict__ rxn_sub,
                               int* __restrict__ woff, int* __restrict__ pay) {
    int t = blockIdx.x * blockDim.x + threadIdx.x;
    if (t < E_SUB) {
        int p = atomicAdd(&woff[rxn_sub[t]], 1);
        pay[p] = t;
    }
}

// Persistent waves pull 8-reaction chunks via global ticket. Per 64-edge
// batch: lane-parallel weight/index precompute; per edge: 5 readlane
// broadcasts (-> SGPRs) + 4 float2 loads + 8 FMA with scalar weights.
__global__ void __launch_bounds__(256)
rxn_fused3(const float* __restrict__ x, const int* __restrict__ met_sub,
           const float* __restrict__ sto_sub,
           const int* __restrict__ off, const int* __restrict__ pay,
           const float2* __restrict__ t2,
           const float* __restrict__ c1, const float* __restrict__ V2,
           const float* __restrict__ c2, const float* __restrict__ log_k,
           const float* __restrict__ ext_sum,
           int* __restrict__ ctr, float* __restrict__ v_out) {
    int lane = threadIdx.x & 63;
    float c1a = c1[lane], c1b = c1[64 + lane];
    float v2a = V2[lane], v2b = V2[64 + lane];
    float c2v = c2[0];
    for (;;) {
        int t0 = 0;
        if (lane == 0) t0 = atomicAdd(ctr, 1);
        int chunk = __builtin_amdgcn_readfirstlane(t0);
        if (chunk >= NCHUNK) break;
        int r0 = chunk * CHUNK;
        int offs = (lane <= CHUNK) ? off[r0 + lane] : 0;
        int start = __shfl(offs, 0);
        int end   = __shfl(offs, CHUNK);
        int cur = 0;
        int cur_start = start;
        int cur_end = __shfl(offs, 1);
        float za = c1a, zb = c1b;
        for (int p0 = start; p0 < end; p0 += 64) {
            int nchunk = end - p0; if (nchunk > 64) nchunk = 64;
            float w00 = 0.0f, w01 = 0.0f, w10 = 0.0f, w11 = 0.0f;
            int idx = 0;
            if (lane < nchunk) {
                int eid = pay[p0 + lane];
                float se = sto_sub[eid];
                float ae = x[met_sub[eid] * 8 + 3];
                float fa = ae * (float)TGRID;
                float fb = (se - 0.5f) * (float)TGRID;
                int ia = (int)fa; ia = ia < 0 ? 0 : (ia > TGRID - 1 ? TGRID - 1 : ia);
                int ib = (int)fb; ib = ib < 0 ? 0 : (ib > TGRID - 1 ? TGRID - 1 : ib);
                float wa = fa - (float)ia, wb = fb - (float)ib;
                float ua = 1.0f - wa, ub = 1.0f - wb;
                w00 = ua * ub; w01 = ua * wb; w10 = wa * ub; w11 = wa * wb;
                idx = ia * TGP + ib;
            }
            for (int j = 0; j < nchunk; ++j) {
                int pe = p0 + j;
                while (pe >= cur_end) {              // wave-uniform finalize
                    float pp = fast_tanh(za) * v2a + fast_tanh(zb) * v2b;
                    #pragma unroll
                    for (int o = 32; o > 0; o >>= 1) pp += __shfl_xor(pp, o);
                    if (lane == 0) {
                        int r = r0 + cur;
                        int n = cur_end - cur_start;
                        float em = ext_sum[r] / (float)(n > 0 ? n : 1);
                        float bv = softplus_f(pp + c2v);
                        float k  = __expf(log_k[r] * 2.302585092994046f);
                        v_out[r] = k * em * bv;
                    }
                    cur++;
                    cur_start = cur_end;
                    cur_end = __shfl(offs, cur + 1);
                    za = c1a; zb = c1b;
                }
                int   si  = __builtin_amdgcn_readlane(idx, j);
                float s00 = bcastf(w00, j);
                float s01 = bcastf(w01, j);
                float s10 = bcastf(w10, j);
                float s11 = bcastf(w11, j);
                const float2* tp = t2 + si * 64 + lane;
                float2 m00 = tp[0];
                float2 m01 = tp[64];
                float2 m10 = tp[TGP * 64];
                float2 m11 = tp[TGP * 64 + 64];
                za = fmaf(s00, m00.x, za); zb = fmaf(s00, m00.y, zb);
                za = fmaf(s01, m01.x, za); zb = fmaf(s01, m01.y, zb);
                za = fmaf(s10, m10.x, za); zb = fmaf(s10, m10.y, zb);
                za = fmaf(s11, m11.x, za); zb = fmaf(s11, m11.y, zb);
            }
        }
        while (cur < CHUNK) {                        // tail finalize
            float pp = fast_tanh(za) * v2a + fast_tanh(zb) * v2b;
            #pragma unroll
            for (int o = 32; o > 0; o >>= 1) pp += __shfl_xor(pp, o);
            if (lane == 0) {
                int r = r0 + cur;
                int n = cur_end - cur_start;
                float em = ext_sum[r] / (float)(n > 0 ? n : 1);
                float bv = softplus_f(pp + c2v);
                float k  = __expf(log_k[r] * 2.302585092994046f);
                v_out[r] = k * em * bv;
            }
            cur++;
            if (cur < CHUNK) {
                cur_start = cur_end;
                cur_end = __shfl(offs, cur + 1);
                za = c1a; zb = c1b;
            }
        }
    }
}

__global__ void cons_kernel(const int* __restrict__ met_sub, const int* __restrict__ rxn_sub,
                            const float* __restrict__ sto_sub, const float* __restrict__ v,
                            float* __restrict__ tot) {
    int e = blockIdx.x * blockDim.x + threadIdx.x;
    if (e < E_SUB)
        atomicAdd(&tot[met_sub[e]], sto_sub[e] * v[rxn_sub[e]] * DT);
}

// atomic-free: thread = reaction, gather met scales over rxn-CSR, fold into v
__global__ void rxn_scale_kernel(const int* __restrict__ off, const int* __restrict__ pay,
                                 const int* __restrict__ met_sub, const float* __restrict__ x,
                                 const float* __restrict__ tot, float* __restrict__ v) {
    int r = blockIdx.x * blockDim.x + threadIdx.x;
    if (r >= N_RXN) return;
    int s = off[r], e = off[r + 1];
    float sc = 1.0f;
    for (int p = s; p < e; ++p) {
        int m = met_sub[pay[p]];
        float tc = tot[m];
        if (tc > 1e-12f) sc = fminf(sc, fminf(x[m * 8 + 3] / tc, 1.0f));
    }
    v[r] *= sc;
}

__global__ void out_kernel(const int* __restrict__ met_sub, const int* __restrict__ rxn_sub,
                           const float* __restrict__ sto_sub,
                           const int* __restrict__ met_prod, const int* __restrict__ rxn_prod,
                           const float* __restrict__ sto_prod,
                           const float* __restrict__ v, float* __restrict__ out) {
    int t = blockIdx.x * blockDim.x + threadIdx.x;
    if (t < E_SUB) {
        atomicAdd(&out[met_sub[t]], -sto_sub[t] * v[rxn_sub[t]]);
    } else if (t < E_SUB + E_PROD) {
        int e = t - E_SUB;
        atomicAdd(&out[met_prod[e]], sto_prod[e] * v[rxn_prod[e]]);
    }
}

extern "C" void kernel_launch(void* const* d_in, const int* in_sizes, int n_in,
                              void* d_out, int out_size, void* d_ws, size_t ws_size,
                              hipStream_t stream) {
    const float* x        = (const float*)d_in[0];
    const int*   met_sub  = (const int*)d_in[1];
    const int*   rxn_sub  = (const int*)d_in[2];
    const float* sto_sub  = (const float*)d_in[3];
    const int*   met_prod = (const int*)d_in[4];
    const int*   rxn_prod = (const int*)d_in[5];
    const float* sto_prod = (const float*)d_in[6];
    const float* W1       = (const float*)d_in[7];
    const float* b1       = (const float*)d_in[8];
    const float* W2       = (const float*)d_in[9];
    const float* b2       = (const float*)d_in[10];
    const float* V1       = (const float*)d_in[11];
    const float* c1       = (const float*)d_in[12];
    const float* V2       = (const float*)d_in[13];
    const float* c2       = (const float*)d_in[14];
    const float* log_k    = (const float*)d_in[15];

    int*   cnt     = (int*)d_ws;                         // N_RXN
    float* ext_sum = (float*)(cnt + N_RXN);              // N_RXN
    int*   ctr     = (int*)(ext_sum + N_RXN);            // 1 (+3 pad)
    float* tot     = (float*)(ctr + 4);                  // N_MET
    int*   off     = (int*)(tot + N_MET);                // N_RXN + 1
    int*   woff    = off + N_RXN + 1;                    // N_RXN
    int*   bsum    = woff + N_RXN;                       // 1024
    int*   pay     = bsum + 1024;                        // E_SUB
    float* v       = (float*)(pay + E_SUB);              // N_RXN
    float* M       = v + N_RXN;                          // 128*128 + 128
    float* t2f     = M + HIDDEN * HIDDEN + HIDDEN;       // NPTS*128

    // zero cnt | ext_sum | ctr (contiguous)
    hipMemsetAsync(cnt, 0, ((size_t)2 * N_RXN + 4) * sizeof(int), stream);

    mm_kernel<<<HIDDEN + 1, HIDDEN, 0, stream>>>(W2, V1, b2, M);
    gtable_kernel<<<(NPTS + BPTS - 1) / BPTS, HIDDEN, 0, stream>>>(W1, b1, M, t2f);
    hist_kernel<<<(E_SUB + 255) / 256, 256, 0, stream>>>(rxn_sub, met_sub, x, cnt, ext_sum);
    scan_l1<<<NB1, 256, 0, stream>>>(cnt, off, bsum);
    scan_l2<<<1, 1024, 0, stream>>>(bsum);
    scan_l3<<<NB1, 256, 0, stream>>>(off, bsum, woff, tot, (float*)d_out);
    scatter_kernel<<<(E_SUB + 255) / 256, 256, 0, stream>>>(rxn_sub, woff, pay);
    rxn_fused3<<<2048, 256, 0, stream>>>(x, met_sub, sto_sub, off, pay, (const float2*)t2f,
                                         c1, V2, c2, log_k, ext_sum, ctr, v);
    cons_kernel<<<(E_SUB + 255) / 256, 256, 0, stream>>>(met_sub, rxn_sub, sto_sub, v, tot);
    rxn_scale_kernel<<<NB1, 256, 0, stream>>>(off, pay, met_sub, x, tot, v);
    out_kernel<<<(E_SUB + E_PROD + 255) / 256, 256, 0, stream>>>(
        met_sub, rxn_sub, sto_sub, met_prod, rxn_prod, sto_prod, v, (float*)d_out);
}

// Round 5
// 325.256 us; speedup vs baseline: 2.0520x; 2.0520x over previous
//
#include <hip/hip_runtime.h>
#include <cmath>

#define N_MET   100000
#define N_RXN   200000
#define E_SUB   400000
#define E_PROD  400000
#define HIDDEN  128
#define MSG_DIM 64
#define DT      0.01f
#define TGRID   32
#define TGP     33
#define NPTS    (TGP * TGP)
#define NB1     ((N_RXN + 255) / 256)          // 782
#define CHUNK   32

__device__ __forceinline__ float fast_tanh(float x) {
    float t = __expf(2.0f * x);
    return 1.0f - 2.0f * __builtin_amdgcn_rcpf(t + 1.0f);
}

__device__ __forceinline__ float softplus_f(float x) {
    return (x > 20.0f) ? x : log1pf(__expf(x));
}

// M[j][d] = sum_m W2[j][m] * V1[m][d]  (128x128), row 128 = b2 @ V1 bias
__global__ void mm_kernel(const float* __restrict__ W2, const float* __restrict__ V1,
                          const float* __restrict__ b2, float* __restrict__ M) {
    int j = blockIdx.x;      // 0..128
    int d = threadIdx.x;     // 0..127
    float acc = 0.0f;
    if (j < HIDDEN) {
        for (int m = 0; m < MSG_DIM; ++m)
            acc = fmaf(W2[j * MSG_DIM + m], V1[m * HIDDEN + d], acc);
        M[j * HIDDEN + d] = acc;
    } else {
        for (int m = 0; m < MSG_DIM; ++m)
            acc = fmaf(b2[m], V1[m * HIDDEN + d], acc);
        M[HIDDEN * HIDDEN + d] = acc;
    }
}

// one block per table point (1089 blocks): full parallelism
__global__ void __launch_bounds__(128)
gtable_kernel(const float* __restrict__ W1, const float* __restrict__ b1,
              const float* __restrict__ M, float* __restrict__ t2f) {
    __shared__ float h_s[HIDDEN];
    int d = threadIdx.x;
    int p = blockIdx.x;
    int ia = p / TGP, ib = p % TGP;
    float a = (float)ia * (1.0f / TGRID);
    float b = 0.5f + (float)ib * (1.0f / TGRID);
    h_s[d] = tanhf(fmaf(a, W1[d], fmaf(b, W1[HIDDEN + d], b1[d])));
    __syncthreads();
    float acc = M[HIDDEN * HIDDEN + d];     // bias row (b2 @ V1)
    #pragma unroll 4
    for (int j = 0; j < HIDDEN; ++j)
        acc = fmaf(h_s[j], M[j * HIDDEN + d], acc);
    if (d < 64) t2f[(p * 64 + d) * 2]            = acc;
    else        t2f[(p * 64 + (d - 64)) * 2 + 1] = acc;
}

// count edges per reaction (ext handled inside fused kernel now)
__global__ void hist_kernel(const int* __restrict__ rxn_sub, int* __restrict__ cnt) {
    int t = blockIdx.x * blockDim.x + threadIdx.x;
    if (t < E_SUB) atomicAdd(&cnt[rxn_sub[t]], 1);
}

__global__ void scan_l1(const int* __restrict__ cnt, int* __restrict__ off,
                        int* __restrict__ bsum) {
    __shared__ int wsum[4];
    int t = threadIdx.x, lane = t & 63, w = t >> 6;
    int i = blockIdx.x * 256 + t;
    int v = (i < N_RXN) ? cnt[i] : 0;
    int s = v;
    #pragma unroll
    for (int d = 1; d < 64; d <<= 1) {
        int u = __shfl_up(s, d);
        if (lane >= d) s += u;
    }
    if (lane == 63) wsum[w] = s;
    __syncthreads();
    int pre = 0;
    #pragma unroll
    for (int q = 0; q < 4; ++q) if (q < w) pre += wsum[q];
    if (i < N_RXN) off[i] = pre + s - v;
    if (t == 255) bsum[blockIdx.x] = pre + s;
}

__global__ void scan_l2(int* __restrict__ bsum) {
    __shared__ int wsum[16];
    int t = threadIdx.x, lane = t & 63, w = t >> 6;
    int v = (t < NB1) ? bsum[t] : 0;
    int s = v;
    #pragma unroll
    for (int d = 1; d < 64; d <<= 1) {
        int u = __shfl_up(s, d);
        if (lane >= d) s += u;
    }
    if (lane == 63) wsum[w] = s;
    __syncthreads();
    int pre = 0;
    #pragma unroll
    for (int q = 0; q < 16; ++q) if (q < w) pre += wsum[q];
    if (t < NB1) bsum[t] = pre + s - v;    // exclusive
}

// finalize scan; zero tot and d_out here
__global__ void scan_l3(int* __restrict__ off, const int* __restrict__ bsum,
                        int* __restrict__ woff, float* __restrict__ tot,
                        float* __restrict__ out) {
    int i = blockIdx.x * blockDim.x + threadIdx.x;
    if (i < N_RXN) {
        int wv = off[i] + bsum[i >> 8];
        off[i] = wv;
        woff[i] = wv;
    }
    if (i < N_MET) { tot[i] = 0.0f; out[i] = 0.0f; }
    if (i == 0) off[N_RXN] = E_SUB;
}

__global__ void scatter_kernel(const int* __restrict__ rxn_sub,
                               int* __restrict__ woff, int* __restrict__ pay) {
    int t = blockIdx.x * blockDim.x + threadIdx.x;
    if (t < E_SUB) {
        int p = atomicAdd(&woff[rxn_sub[t]], 1);
        pay[p] = t;
    }
}

// Round-3-proven structure: wave = 32 consecutive reactions, static chunks.
// Additions: ext accumulated inline; per-chunk cons sweep (tot atomics) using
// LDS-cached v — replaces hist-ext and cons_kernel dispatches.
__global__ void __launch_bounds__(256)
rxn_fused4(const float* __restrict__ x, const int* __restrict__ met_sub,
           const int* __restrict__ rxn_sub, const float* __restrict__ sto_sub,
           const int* __restrict__ off, const int* __restrict__ pay,
           const float2* __restrict__ t2,
           const float* __restrict__ c1, const float* __restrict__ V2,
           const float* __restrict__ c2, const float* __restrict__ log_k,
           float* __restrict__ v_out, float* __restrict__ tot) {
    __shared__ float vbuf[4][CHUNK];
    int lane = threadIdx.x & 63;
    int wslot = threadIdx.x >> 6;
    int wave = (blockIdx.x * blockDim.x + threadIdx.x) >> 6;
    int nwaves = (gridDim.x * blockDim.x) >> 6;
    float c1a = c1[lane], c1b = c1[64 + lane];
    float v2a = V2[lane], v2b = V2[64 + lane];
    float c2v = c2[0];
    for (int chunk = wave; chunk * CHUNK < N_RXN; chunk += nwaves) {
        int r0 = chunk * CHUNK;
        int offs = (lane <= CHUNK) ? off[r0 + lane] : 0;
        int start = __shfl(offs, 0);
        int end   = __shfl(offs, CHUNK);
        int cur = 0;
        int cur_start = start;
        int cur_end = __shfl(offs, 1);
        float za = c1a, zb = c1b, eacc = 0.0f;
        for (int p0 = start; p0 < end; p0 += 64) {
            int nchunk = end - p0; if (nchunk > 64) nchunk = 64;
            float ae = 0.0f, se = 1.0f, xeb = 0.0f;
            if (lane < nchunk) {
                int eid = pay[p0 + lane];
                se = sto_sub[eid];
                int me = met_sub[eid];
                ae = x[me * 8 + 3];
                xeb = x[me * 8 + 4];
            }
            for (int j = 0; j < nchunk; ++j) {
                int pe = p0 + j;
                while (pe >= cur_end) {              // wave-uniform finalize
                    float pp = fast_tanh(za) * v2a + fast_tanh(zb) * v2b;
                    #pragma unroll
                    for (int o = 32; o > 0; o >>= 1) pp += __shfl_xor(pp, o);
                    int r = r0 + cur;
                    int n = cur_end - cur_start;
                    float em = eacc / (float)(n > 0 ? n : 1);
                    if (lane == 0) {
                        float bv = softplus_f(pp + c2v);
                        float k  = __expf(log_k[r] * 2.302585092994046f);
                        float vr = k * em * bv;
                        v_out[r] = vr;
                        vbuf[wslot][cur] = vr;
                    }
                    cur++;
                    cur_start = cur_end;
                    cur_end = __shfl(offs, cur + 1);
                    za = c1a; zb = c1b; eacc = 0.0f;
                }
                float a = __shfl(ae, j);
                float b = __shfl(se, j);
                eacc += __shfl(xeb, j);
                float fa = a * (float)TGRID;
                float fb = (b - 0.5f) * (float)TGRID;
                int ia = (int)fa; ia = ia < 0 ? 0 : (ia > TGRID - 1 ? TGRID - 1 : ia);
                int ib = (int)fb; ib = ib < 0 ? 0 : (ib > TGRID - 1 ? TGRID - 1 : ib);
                float wa = fa - (float)ia;
                float wb = fb - (float)ib;
                const float2* tp = t2 + (ia * TGP + ib) * 64 + lane;
                float2 m00 = tp[0];
                float2 m01 = tp[64];
                float2 m10 = tp[TGP * 64];
                float2 m11 = tp[TGP * 64 + 64];
                float g0x = fmaf(wb, m01.x - m00.x, m00.x);
                float g0y = fmaf(wb, m01.y - m00.y, m00.y);
                float g1x = fmaf(wb, m11.x - m10.x, m10.x);
                float g1y = fmaf(wb, m11.y - m10.y, m10.y);
                za += fmaf(wa, g1x - g0x, g0x);
                zb += fmaf(wa, g1y - g0y, g0y);
            }
        }
        while (cur < CHUNK) {                        // tail finalize
            float pp = fast_tanh(za) * v2a + fast_tanh(zb) * v2b;
            #pragma unroll
            for (int o = 32; o > 0; o >>= 1) pp += __shfl_xor(pp, o);
            int r = r0 + cur;
            int n = cur_end - cur_start;
            float em = eacc / (float)(n > 0 ? n : 1);
            if (lane == 0) {
                float bv = softplus_f(pp + c2v);
                float k  = __expf(log_k[r] * 2.302585092994046f);
                float vr = k * em * bv;
                v_out[r] = vr;
                vbuf[wslot][cur] = vr;
            }
            cur++;
            if (cur < CHUNK) {
                cur_start = cur_end;
                cur_end = __shfl(offs, cur + 1);
                za = c1a; zb = c1b; eacc = 0.0f;
            }
        }
        // cons sweep: tot[met] += sto * v * DT  (v from LDS, loads warm in L2)
        for (int p0 = start; p0 < end; p0 += 64) {
            int nchunk = end - p0; if (nchunk > 64) nchunk = 64;
            if (lane < nchunk) {
                int eid = pay[p0 + lane];
                int r   = rxn_sub[eid];
                float vv = vbuf[wslot][r - r0];
                atomicAdd(&tot[met_sub[eid]], sto_sub[eid] * vv * DT);
            }
        }
    }
}

// atomic-free: thread = reaction, gather met scales over rxn-CSR, fold into v
__global__ void rxn_scale_kernel(const int* __restrict__ off, const int* __restrict__ pay,
                                 const int* __restrict__ met_sub, const float* __restrict__ x,
                                 const float* __restrict__ tot, float* __restrict__ v) {
    int r = blockIdx.x * blockDim.x + threadIdx.x;
    if (r >= N_RXN) return;
    int s = off[r], e = off[r + 1];
    float sc = 1.0f;
    for (int p = s; p < e; ++p) {
        int m = met_sub[pay[p]];
        float tc = tot[m];
        if (tc > 1e-12f) sc = fminf(sc, fminf(x[m * 8 + 3] / tc, 1.0f));
    }
    v[r] *= sc;
}

__global__ void out_kernel(const int* __restrict__ met_sub, const int* __restrict__ rxn_sub,
                           const float* __restrict__ sto_sub,
                           const int* __restrict__ met_prod, const int* __restrict__ rxn_prod,
                           const float* __restrict__ sto_prod,
                           const float* __restrict__ v, float* __restrict__ out) {
    int t = blockIdx.x * blockDim.x + threadIdx.x;
    if (t < E_SUB) {
        atomicAdd(&out[met_sub[t]], -sto_sub[t] * v[rxn_sub[t]]);
    } else if (t < E_SUB + E_PROD) {
        int e = t - E_SUB;
        atomicAdd(&out[met_prod[e]], sto_prod[e] * v[rxn_prod[e]]);
    }
}

extern "C" void kernel_launch(void* const* d_in, const int* in_sizes, int n_in,
                              void* d_out, int out_size, void* d_ws, size_t ws_size,
                              hipStream_t stream) {
    const float* x        = (const float*)d_in[0];
    const int*   met_sub  = (const int*)d_in[1];
    const int*   rxn_sub  = (const int*)d_in[2];
    const float* sto_sub  = (const float*)d_in[3];
    const int*   met_prod = (const int*)d_in[4];
    const int*   rxn_prod = (const int*)d_in[5];
    const float* sto_prod = (const float*)d_in[6];
    const float* W1       = (const float*)d_in[7];
    const float* b1       = (const float*)d_in[8];
    const float* W2       = (const float*)d_in[9];
    const float* b2       = (const float*)d_in[10];
    const float* V1       = (const float*)d_in[11];
    const float* c1       = (const float*)d_in[12];
    const float* V2       = (const float*)d_in[13];
    const float* c2       = (const float*)d_in[14];
    const float* log_k    = (const float*)d_in[15];

    int*   cnt  = (int*)d_ws;                        // N_RXN
    float* tot  = (float*)(cnt + N_RXN);             // N_MET
    int*   off  = (int*)(tot + N_MET);               // N_RXN + 1
    int*   woff = off + N_RXN + 1;                   // N_RXN
    int*   bsum = woff + N_RXN;                      // 1024
    int*   pay  = bsum + 1024;                       // E_SUB
    float* v    = (float*)(pay + E_SUB);             // N_RXN
    float* M    = v + N_RXN;                         // 128*128 + 128
    float* t2f  = M + HIDDEN * HIDDEN + HIDDEN;      // NPTS*128

    hipMemsetAsync(cnt, 0, (size_t)N_RXN * sizeof(int), stream);

    mm_kernel<<<HIDDEN + 1, HIDDEN, 0, stream>>>(W2, V1, b2, M);
    gtable_kernel<<<NPTS, HIDDEN, 0, stream>>>(W1, b1, M, t2f);
    hist_kernel<<<(E_SUB + 255) / 256, 256, 0, stream>>>(rxn_sub, cnt);
    scan_l1<<<NB1, 256, 0, stream>>>(cnt, off, bsum);
    scan_l2<<<1, 1024, 0, stream>>>(bsum);
    scan_l3<<<NB1, 256, 0, stream>>>(off, bsum, woff, tot, (float*)d_out);
    scatter_kernel<<<(E_SUB + 255) / 256, 256, 0, stream>>>(rxn_sub, woff, pay);
    rxn_fused4<<<1563, 256, 0, stream>>>(x, met_sub, rxn_sub, sto_sub, off, pay,
                                         (const float2*)t2f, c1, V2, c2, log_k, v, tot);
    rxn_scale_kernel<<<NB1, 256, 0, stream>>>(off, pay, met_sub, x, tot, v);
    out_kernel<<<(E_SUB + E_PROD + 255) / 256, 256, 0, stream>>>(
        met_sub, rxn_sub, sto_sub, met_prod, rxn_prod, sto_prod, v, (float*)d_out);
}